// Round 1
// baseline (606.680 us; speedup 1.0000x reference)
//
#include <hip/hip_runtime.h>
#include <cstdint>
#include <cstddef>

#define DEVI __device__ __forceinline__

typedef unsigned short u16;
typedef __bf16 bf16_t;
typedef bf16_t bf16x8 __attribute__((ext_vector_type(8)));
typedef float f32x4 __attribute__((ext_vector_type(4)));

// problem sizes (fixed)
constexpr int BB = 2, SS = 2048, HID = 2048, NH = 16, DK = 128, DV = 128;
constexpr int MR = BB * SS;  // 4096 rows of x
constexpr int KD = HID;      // 2048 inner dim

DEVI u16 f2bf(float f) {
  union { float f; uint32_t u; } v; v.f = f;
  uint32_t u = v.u;
  uint32_t r = u + 0x7FFFu + ((u >> 16) & 1u);  // RNE
  return (u16)(r >> 16);
}
DEVI float bf2f(u16 h) {
  union { uint32_t u; float f; } v; v.u = ((uint32_t)h) << 16;
  return v.f;
}
DEVI f32x4 mfma16(bf16x8 a, bf16x8 b, f32x4 c) {
  return __builtin_amdgcn_mfma_f32_16x16x32_bf16(a, b, c, 0, 0, 0);
}

// ---------------------------------------------------------------------------
// Weight transpose + cast: W[k][n] fp32 -> WT[n][k] bf16  (NT-GEMM B operand)
// ---------------------------------------------------------------------------
__global__ __launch_bounds__(256) void wtrans_kernel(
    const float* __restrict__ wq, const float* __restrict__ wk,
    const float* __restrict__ wv, const float* __restrict__ wg,
    const float* __restrict__ wo, u16* __restrict__ wt)
{
  __shared__ float t[32][33];
  const float* srcs[5] = {wq, wk, wv, wg, wo};
  const float* W = srcs[blockIdx.z];
  u16* dst = wt + (size_t)blockIdx.z * (size_t)KD * HID;
  int tx = threadIdx.x, ty = threadIdx.y;
  int c0 = blockIdx.x * 32, r0 = blockIdx.y * 32;
#pragma unroll
  for (int i = 0; i < 4; ++i)
    t[ty + i * 8][tx] = W[(size_t)(r0 + ty + i * 8) * HID + c0 + tx];
  __syncthreads();
#pragma unroll
  for (int i = 0; i < 4; ++i) {
    int n = c0 + ty + i * 8;
    int k = r0 + tx;
    dst[(size_t)n * KD + k] = f2bf(t[tx][ty + i * 8]);
  }
}

// ---------------------------------------------------------------------------
// GEMM core: C[128x128] = A[128xK] * Bt[128xK]^T, bf16 MFMA 16x16x32.
// 4 waves, each 64x64 (4x4 frags). LDS tiles 128x64 bf16, 128B rows,
// XOR-swizzled (byte ^= (row&7)<<4) so ds_read_b128 is conflict-free.
// ---------------------------------------------------------------------------
template<bool AF32>
DEVI void gemm_core(const void* __restrict__ Ap, const u16* __restrict__ Bt,
                    int m0, int n0, u16* sA, u16* sB, f32x4 (&acc)[4][4])
{
  const int tid = threadIdx.x;
  const int lane = tid & 63;
  const int wave = tid >> 6;
  const int wr = wave >> 1, wc = wave & 1;
  const int lhi = lane >> 4, llo = lane & 15;

  for (int kt = 0; kt < KD / 64; ++kt) {
    __syncthreads();
    if (AF32) {
      const float* A = (const float*)Ap;
#pragma unroll
      for (int i = 0; i < 8; ++i) {
        int c = tid + i * 256;              // 2048 chunks of 4 fp32
        int row = c >> 4, col4 = c & 15;
        float4 v = *(const float4*)(A + (size_t)(m0 + row) * KD + kt * 64 + col4 * 4);
        ushort4 hh;
        hh.x = f2bf(v.x); hh.y = f2bf(v.y); hh.z = f2bf(v.z); hh.w = f2bf(v.w);
        *(ushort4*)((char*)sA + row * 128 + ((col4 * 8) ^ ((row & 7) << 4))) = hh;
      }
    } else {
      const u16* A = (const u16*)Ap;
#pragma unroll
      for (int i = 0; i < 4; ++i) {
        int c = tid + i * 256;              // 1024 chunks of 8 bf16
        int row = c >> 3, col8 = c & 7;
        uint4 v = *(const uint4*)(A + (size_t)(m0 + row) * KD + kt * 64 + col8 * 8);
        *(uint4*)((char*)sA + row * 128 + ((col8 * 16) ^ ((row & 7) << 4))) = v;
      }
    }
#pragma unroll
    for (int i = 0; i < 4; ++i) {
      int c = tid + i * 256;
      int row = c >> 3, col8 = c & 7;
      uint4 v = *(const uint4*)(Bt + (size_t)(n0 + row) * KD + kt * 64 + col8 * 8);
      *(uint4*)((char*)sB + row * 128 + ((col8 * 16) ^ ((row & 7) << 4))) = v;
    }
    __syncthreads();
#pragma unroll
    for (int ks = 0; ks < 2; ++ks) {
      const int kb = ks * 64 + lhi * 16;
      bf16x8 af[4], bfr[4];
#pragma unroll
      for (int mi = 0; mi < 4; ++mi) {
        int row = wr * 64 + mi * 16 + llo;
        af[mi] = *(const bf16x8*)((char*)sA + row * 128 + (kb ^ ((row & 7) << 4)));
      }
#pragma unroll
      for (int ni = 0; ni < 4; ++ni) {
        int row = wc * 64 + ni * 16 + llo;
        bfr[ni] = *(const bf16x8*)((char*)sB + row * 128 + (kb ^ ((row & 7) << 4)));
      }
#pragma unroll
      for (int mi = 0; mi < 4; ++mi)
#pragma unroll
        for (int ni = 0; ni < 4; ++ni)
          acc[mi][ni] = mfma16(af[mi], bfr[ni], acc[mi][ni]);
    }
  }
}

// ---------------------------------------------------------------------------
// Projections: z=0 Q, z=1 K -> (b,h,s,dk) bf16; z=2 V -> (b,h,dv,s) bf16
// (transposed for PV); z=3 gate -> silu -> (b,s,hid) bf16.
// ---------------------------------------------------------------------------
__global__ __launch_bounds__(256) void proj_kernel(
    const float* __restrict__ x, const u16* __restrict__ wtBase,
    const float* __restrict__ bq, const float* __restrict__ bk,
    const float* __restrict__ bv, const float* __restrict__ bg,
    u16* __restrict__ qb, u16* __restrict__ kb,
    u16* __restrict__ vtb, u16* __restrict__ gb)
{
  __shared__ u16 sA[128 * 64];
  __shared__ u16 sB[128 * 64];
  const int z = blockIdx.z;
  const u16* Bt = wtBase + (size_t)z * (size_t)KD * HID;
  f32x4 acc[4][4];
  const f32x4 zero = {0.f, 0.f, 0.f, 0.f};
#pragma unroll
  for (int mi = 0; mi < 4; ++mi)
#pragma unroll
    for (int ni = 0; ni < 4; ++ni) acc[mi][ni] = zero;

  const int m0 = blockIdx.x * 128, n0 = blockIdx.y * 128;
  gemm_core<true>(x, Bt, m0, n0, sA, sB, acc);

  const float* bias = (z == 0) ? bq : (z == 1) ? bk : (z == 2) ? bv : bg;
  const int lane = threadIdx.x & 63, wave = threadIdx.x >> 6;
  const int wr = wave >> 1, wc = wave & 1;
  const int lhi = lane >> 4, llo = lane & 15;
#pragma unroll
  for (int mi = 0; mi < 4; ++mi) {
#pragma unroll
    for (int ni = 0; ni < 4; ++ni) {
      int row0 = m0 + wr * 64 + mi * 16 + lhi * 4;
      int n = n0 + wc * 64 + ni * 16 + llo;
      float bsn = bias[n];
      if (z == 2) {
        int b = row0 >> 11, s0 = row0 & (SS - 1);
        int h = n >> 7, j = n & 127;
        ushort4 hv;
        hv.x = f2bf(acc[mi][ni][0] + bsn);
        hv.y = f2bf(acc[mi][ni][1] + bsn);
        hv.z = f2bf(acc[mi][ni][2] + bsn);
        hv.w = f2bf(acc[mi][ni][3] + bsn);
        *(ushort4*)(vtb + ((size_t)((b * NH + h) * DV + j)) * SS + s0) = hv;
      } else if (z == 3) {
#pragma unroll
        for (int r = 0; r < 4; ++r) {
          int m = row0 + r;
          float c = acc[mi][ni][r] + bsn;
          float sg = c / (1.0f + expf(-c));
          gb[(size_t)m * HID + n] = f2bf(sg);
        }
      } else {
        u16* dst = (z == 0) ? qb : kb;
#pragma unroll
        for (int r = 0; r < 4; ++r) {
          int m = row0 + r;
          int b = m >> 11, s = m & (SS - 1);
          int h = n >> 7, j = n & 127;
          dst[((size_t)((b * NH + h) * SS + s)) * DK + j] = f2bf(acc[mi][ni][r] + bsn);
        }
      }
    }
  }
}

// ---------------------------------------------------------------------------
// Retention: per (b,h, 128-row q tile). Stream 64-row K/V tiles with decay
// mask gamma^(n-m) applied as gamma^n * gamma^-m. Outputs fp32 ret (b,h,s,dv)
// and atomic per-(b,h) sum/sumsq for GroupNorm.
// ---------------------------------------------------------------------------
__global__ __launch_bounds__(256) void retention_kernel(
    const u16* __restrict__ qb, const u16* __restrict__ kb,
    const u16* __restrict__ vtb, const float* __restrict__ gamma,
    float* __restrict__ ret, float* __restrict__ stats)
{
  __shared__ u16 sK[64 * 128];   // [m 0..63][k 0..127], 256B rows, swz (row&15)<<4
  __shared__ u16 sV[128 * 64];   // [dv 0..127][m 0..63], 128B rows, swz (row&7)<<4
  __shared__ u16 sP[4][32 * 64]; // per-wave P, 128B rows, swz (row&7)<<4
  __shared__ float red[8];

  const int bh = blockIdx.y;
  const int n0 = blockIdx.x * 128;
  const int h = bh & (NH - 1);
  const float lg2 = log2f(gamma[h]);

  const int tid = threadIdx.x, lane = tid & 63, wave = tid >> 6;
  const int lhi = lane >> 4, llo = lane & 15;
  const int qrow = n0 + wave * 32;

  // Q fragments in registers (reused across all m tiles)
  const u16* qbase = qb + ((size_t)bh * SS + qrow) * DK;
  bf16x8 aq[2][4];
#pragma unroll
  for (int mi = 0; mi < 2; ++mi)
#pragma unroll
    for (int ks = 0; ks < 4; ++ks)
      aq[mi][ks] = *(const bf16x8*)(qbase + (size_t)(mi * 16 + llo) * DK + ks * 32 + lhi * 8);

  float rdec[2][4];
#pragma unroll
  for (int mi = 0; mi < 2; ++mi)
#pragma unroll
    for (int r = 0; r < 4; ++r)
      rdec[mi][r] = exp2f(lg2 * (float)(qrow + mi * 16 + lhi * 4 + r));

  const f32x4 zero = {0.f, 0.f, 0.f, 0.f};
  f32x4 oacc[2][8];
#pragma unroll
  for (int mi = 0; mi < 2; ++mi)
#pragma unroll
    for (int nj = 0; nj < 8; ++nj) oacc[mi][nj] = zero;

  const u16* kbase = kb + (size_t)bh * SS * DK;
  const u16* vbase = vtb + (size_t)bh * DV * SS;
  const int mtiles = n0 / 64 + 2;

  for (int mt = 0; mt < mtiles; ++mt) {
    const int m0 = mt * 64;
    __syncthreads();
    // stage K tile (64 x 128 bf16)
#pragma unroll
    for (int i = 0; i < 4; ++i) {
      int c = tid + i * 256;
      int row = c >> 4, col8 = c & 15;
      uint4 v = *(const uint4*)(kbase + (size_t)(m0 + row) * DK + col8 * 8);
      *(uint4*)((char*)sK + row * 256 + ((col8 * 16) ^ ((row & 15) << 4))) = v;
    }
    // stage Vt tile (128 x 64 bf16)
#pragma unroll
    for (int i = 0; i < 4; ++i) {
      int c = tid + i * 256;
      int row = c >> 3, col8 = c & 7;
      uint4 v = *(const uint4*)(vbase + (size_t)row * SS + m0 + col8 * 8);
      *(uint4*)((char*)sV + row * 128 + ((col8 * 16) ^ ((row & 7) << 4))) = v;
    }
    __syncthreads();

    // QK^T
    f32x4 sacc[2][4];
#pragma unroll
    for (int mi = 0; mi < 2; ++mi)
#pragma unroll
      for (int ni = 0; ni < 4; ++ni) sacc[mi][ni] = zero;
#pragma unroll
    for (int ks = 0; ks < 4; ++ks) {
      const int kbyte = ks * 64 + lhi * 16;
      bf16x8 bk_[4];
#pragma unroll
      for (int ni = 0; ni < 4; ++ni) {
        int row = ni * 16 + llo;
        bk_[ni] = *(const bf16x8*)((char*)sK + row * 256 + (kbyte ^ ((row & 15) << 4)));
      }
#pragma unroll
      for (int mi = 0; mi < 2; ++mi)
#pragma unroll
        for (int ni = 0; ni < 4; ++ni)
          sacc[mi][ni] = mfma16(aq[mi][ks], bk_[ni], sacc[mi][ni]);
    }

    // decay + causal mask + bf16 P into per-wave LDS
    float cfac[4];
#pragma unroll
    for (int ni = 0; ni < 4; ++ni)
      cfac[ni] = exp2f(-lg2 * (float)(m0 + ni * 16 + llo));
    const bool masked = (m0 + 63 > qrow);
    char* myP = (char*)&sP[wave][0];
#pragma unroll
    for (int mi = 0; mi < 2; ++mi) {
#pragma unroll
      for (int ni = 0; ni < 4; ++ni) {
#pragma unroll
        for (int r = 0; r < 4; ++r) {
          int prow = mi * 16 + lhi * 4 + r;
          int pcol = ni * 16 + llo;
          float w = rdec[mi][r] * cfac[ni];
          if (masked && (qrow + prow < m0 + pcol)) w = 0.0f;
          float p = sacc[mi][ni][r] * w;
          *(u16*)(myP + prow * 128 + ((pcol * 2) ^ ((prow & 7) << 4))) = f2bf(p);
        }
      }
    }

    // PV (same-wave LDS write->read; compiler inserts lgkmcnt)
#pragma unroll
    for (int ks2 = 0; ks2 < 2; ++ks2) {
      const int kbyte = ks2 * 64 + lhi * 16;
      bf16x8 pa[2];
#pragma unroll
      for (int mi = 0; mi < 2; ++mi) {
        int row = mi * 16 + llo;
        pa[mi] = *(const bf16x8*)(myP + row * 128 + (kbyte ^ ((row & 7) << 4)));
      }
#pragma unroll
      for (int nj = 0; nj < 8; ++nj) {
        int row = nj * 16 + llo;
        bf16x8 vb = *(const bf16x8*)((char*)sV + row * 128 + (kbyte ^ ((row & 7) << 4)));
#pragma unroll
        for (int mi = 0; mi < 2; ++mi)
          oacc[mi][nj] = mfma16(pa[mi], vb, oacc[mi][nj]);
      }
    }
  }

  // write ret + local stats
  float lsum = 0.f, lsq = 0.f;
  float* rbase = ret + ((size_t)bh * SS + qrow) * DV;
#pragma unroll
  for (int mi = 0; mi < 2; ++mi) {
#pragma unroll
    for (int nj = 0; nj < 8; ++nj) {
      int prow0 = mi * 16 + lhi * 4;
      int j = nj * 16 + llo;
#pragma unroll
      for (int r = 0; r < 4; ++r) {
        float v = oacc[mi][nj][r];
        rbase[(size_t)(prow0 + r) * DV + j] = v;
        lsum += v; lsq += v * v;
      }
    }
  }
#pragma unroll
  for (int off = 32; off > 0; off >>= 1) {
    lsum += __shfl_down(lsum, off, 64);
    lsq  += __shfl_down(lsq,  off, 64);
  }
  if (lane == 0) { red[wave * 2] = lsum; red[wave * 2 + 1] = lsq; }
  __syncthreads();
  if (tid == 0) {
    float s = red[0] + red[2] + red[4] + red[6];
    float q = red[1] + red[3] + red[5] + red[7];
    atomicAdd(&stats[bh * 2], s);
    atomicAdd(&stats[bh * 2 + 1], q);
  }
}

// ---------------------------------------------------------------------------
// GroupNorm (per b,head over s,dv) * gate -> A2 bf16 (b,s,hid)
// ---------------------------------------------------------------------------
__global__ __launch_bounds__(256) void normgate_kernel(
    const float* __restrict__ ret, const u16* __restrict__ gb,
    const float* __restrict__ stats, const float* __restrict__ gn_w,
    const float* __restrict__ gn_b, u16* __restrict__ a2)
{
  const int idx4 = (blockIdx.x * 256 + threadIdx.x) * 4;
  const int bh = idx4 >> 18;              // / (S*DV)
  const int rem = idx4 & (SS * DV - 1);
  const int s = rem >> 7;
  const int dv = rem & (DV - 1);
  const float inv = 1.0f / (float)(SS * DV);
  float mean = stats[bh * 2] * inv;
  float var = stats[bh * 2 + 1] * inv - mean * mean;
  float rstd = rsqrtf(var + 1e-5f);
  const int b = bh >> 4, h = bh & (NH - 1);
  const int hd = h * DV + dv;
  float4 rv = *(const float4*)(ret + idx4);
  float4 w4 = *(const float4*)(gn_w + hd);
  float4 b4 = *(const float4*)(gn_b + hd);
  size_t gidx = ((size_t)(b * SS + s)) * HID + hd;
  ushort4 g4 = *(const ushort4*)(gb + gidx);
  ushort4 o;
  o.x = f2bf(bf2f(g4.x) * ((rv.x - mean) * rstd * w4.x + b4.x));
  o.y = f2bf(bf2f(g4.y) * ((rv.y - mean) * rstd * w4.y + b4.y));
  o.z = f2bf(bf2f(g4.z) * ((rv.z - mean) * rstd * w4.z + b4.z));
  o.w = f2bf(bf2f(g4.w) * ((rv.w - mean) * rstd * w4.w + b4.w));
  *(ushort4*)(a2 + gidx) = o;
}

// ---------------------------------------------------------------------------
// Final GEMM: out = A2 @ wo + bo, fp32 out
// ---------------------------------------------------------------------------
__global__ __launch_bounds__(256) void final_kernel(
    const u16* __restrict__ a2, const u16* __restrict__ woT,
    const float* __restrict__ bo, float* __restrict__ out)
{
  __shared__ u16 sA[128 * 64];
  __shared__ u16 sB[128 * 64];
  f32x4 acc[4][4];
  const f32x4 zero = {0.f, 0.f, 0.f, 0.f};
#pragma unroll
  for (int mi = 0; mi < 4; ++mi)
#pragma unroll
    for (int ni = 0; ni < 4; ++ni) acc[mi][ni] = zero;

  const int m0 = blockIdx.x * 128, n0 = blockIdx.y * 128;
  gemm_core<false>(a2, woT, m0, n0, sA, sB, acc);

  const int lane = threadIdx.x & 63, wave = threadIdx.x >> 6;
  const int wr = wave >> 1, wc = wave & 1;
  const int lhi = lane >> 4, llo = lane & 15;
#pragma unroll
  for (int mi = 0; mi < 4; ++mi) {
#pragma unroll
    for (int ni = 0; ni < 4; ++ni) {
      int row0 = m0 + wr * 64 + mi * 16 + lhi * 4;
      int n = n0 + wc * 64 + ni * 16 + llo;
      float bn = bo[n];
#pragma unroll
      for (int r = 0; r < 4; ++r)
        out[(size_t)(row0 + r) * HID + n] = acc[mi][ni][r] + bn;
    }
  }
}

// ---------------------------------------------------------------------------
extern "C" void kernel_launch(void* const* d_in, const int* in_sizes, int n_in,
                              void* d_out, int out_size, void* d_ws, size_t ws_size,
                              hipStream_t stream) {
  const float* x    = (const float*)d_in[0];
  const float* wq   = (const float*)d_in[1];
  const float* bq   = (const float*)d_in[2];
  const float* wk   = (const float*)d_in[3];
  const float* bk   = (const float*)d_in[4];
  const float* wv   = (const float*)d_in[5];
  const float* bv   = (const float*)d_in[6];
  const float* wg   = (const float*)d_in[7];
  const float* bg   = (const float*)d_in[8];
  const float* wo   = (const float*)d_in[9];
  const float* bo   = (const float*)d_in[10];
  const float* gn_w = (const float*)d_in[11];
  const float* gn_b = (const float*)d_in[12];
  const float* gam  = (const float*)d_in[13];

  char* ws = (char*)d_ws;
  // layout (bytes):
  u16* wT    = (u16*)(ws);                  // 5 * 8,388,608   = 41,943,040
  u16* qb    = (u16*)(ws + 41943040);       // 16,777,216
  u16* kbuf  = (u16*)(ws + 58720256);       // 16,777,216
  u16* vtb   = (u16*)(ws + 75497472);       // 16,777,216
  u16* gb    = (u16*)(ws + 92274688);       // 16,777,216
  float* ret = (float*)(ws + 109051904);    // 33,554,432
  float* st  = (float*)(ws + 142606336);    // 256
  u16* a2    = qb;                          // reuse (qb dead after retention)

  hipMemsetAsync(st, 0, 256, stream);
  wtrans_kernel<<<dim3(64, 64, 5), dim3(32, 8), 0, stream>>>(wq, wk, wv, wg, wo, wT);
  proj_kernel<<<dim3(32, 16, 4), 256, 0, stream>>>(x, wT, bq, bk, bv, bg, qb, kbuf, vtb, gb);
  retention_kernel<<<dim3(16, 32), 256, 0, stream>>>(qb, kbuf, vtb, gam, ret, st);
  normgate_kernel<<<16384, 256, 0, stream>>>(ret, gb, st, gn_w, gn_b, a2);
  final_kernel<<<dim3(32, 16), 256, 0, stream>>>(a2, wT + (size_t)4 * KD * HID, bo, (float*)d_out);
}

// Round 2
// 555.740 us; speedup vs baseline: 1.0917x; 1.0917x over previous
//
#include <hip/hip_runtime.h>
#include <cstdint>
#include <cstddef>

#define DEVI __device__ __forceinline__

typedef unsigned short u16;
typedef __bf16 bf16_t;
typedef bf16_t bf16x8 __attribute__((ext_vector_type(8)));
typedef float f32x4 __attribute__((ext_vector_type(4)));

// problem sizes (fixed)
constexpr int BB = 2, SS = 2048, HID = 2048, NH = 16, DK = 128, DV = 128;
constexpr int MR = BB * SS;  // 4096 rows of x
constexpr int KD = HID;      // 2048 inner dim

DEVI u16 f2bf(float f) {
  union { float f; uint32_t u; } v; v.f = f;
  uint32_t u = v.u;
  uint32_t r = u + 0x7FFFu + ((u >> 16) & 1u);  // RNE
  return (u16)(r >> 16);
}
DEVI float bf2f(u16 h) {
  union { uint32_t u; float f; } v; v.u = ((uint32_t)h) << 16;
  return v.f;
}
DEVI f32x4 mfma16(bf16x8 a, bf16x8 b, f32x4 c) {
  return __builtin_amdgcn_mfma_f32_16x16x32_bf16(a, b, c, 0, 0, 0);
}
// async global->LDS, 16B per lane. LDS dest = wave-uniform base + lane*16.
DEVI void gload16(const u16* g, u16* l) {
  __builtin_amdgcn_global_load_lds(
      (const __attribute__((address_space(1))) uint32_t*)g,
      (__attribute__((address_space(3))) uint32_t*)l, 16, 0, 0);
}

// ---------------------------------------------------------------------------
// x fp32 -> bf16 (pre-cast so GEMM A-staging is pure global_load_lds)
// ---------------------------------------------------------------------------
__global__ __launch_bounds__(256) void castx_kernel(
    const float* __restrict__ x, u16* __restrict__ xb)
{
  size_t i = ((size_t)blockIdx.x * 256 + threadIdx.x) * 8;
  float4 a = *(const float4*)(x + i);
  float4 b = *(const float4*)(x + i + 4);
  ushort4 lo, hi;
  lo.x = f2bf(a.x); lo.y = f2bf(a.y); lo.z = f2bf(a.z); lo.w = f2bf(a.w);
  hi.x = f2bf(b.x); hi.y = f2bf(b.y); hi.z = f2bf(b.z); hi.w = f2bf(b.w);
  *(ushort4*)(xb + i) = lo;
  *(ushort4*)(xb + i + 4) = hi;
}

// ---------------------------------------------------------------------------
// Weight transpose + cast: W[k][n] fp32 -> WT[n][k] bf16  (NT-GEMM B operand)
// ---------------------------------------------------------------------------
__global__ __launch_bounds__(256) void wtrans_kernel(
    const float* __restrict__ wq, const float* __restrict__ wk,
    const float* __restrict__ wv, const float* __restrict__ wg,
    const float* __restrict__ wo, u16* __restrict__ wt)
{
  __shared__ float t[32][33];
  const float* srcs[5] = {wq, wk, wv, wg, wo};
  const float* W = srcs[blockIdx.z];
  u16* dst = wt + (size_t)blockIdx.z * (size_t)KD * HID;
  int tx = threadIdx.x, ty = threadIdx.y;
  int c0 = blockIdx.x * 32, r0 = blockIdx.y * 32;
#pragma unroll
  for (int i = 0; i < 4; ++i)
    t[ty + i * 8][tx] = W[(size_t)(r0 + ty + i * 8) * HID + c0 + tx];
  __syncthreads();
#pragma unroll
  for (int i = 0; i < 4; ++i) {
    int n = c0 + ty + i * 8;
    int k = r0 + tx;
    dst[(size_t)n * KD + k] = f2bf(t[tx][ty + i * 8]);
  }
}

// ---------------------------------------------------------------------------
// GEMM core: C[128x128] = A[128xK] * Bt[128xK]^T, bf16 MFMA 16x16x32.
// m97 structure: global_load_lds width-16 staging (linear LDS dest,
// inverse-swizzled global source), swizzled ds_read_b128 (conflict-free).
// 4 waves, each 64x64 (4x4 frags). LDS tiles 128x64 bf16 (128B rows).
// ---------------------------------------------------------------------------
DEVI void gemm_core(const u16* __restrict__ A, const u16* __restrict__ Bt,
                    int m0, int n0, u16* sA, u16* sB, f32x4 (&acc)[4][4])
{
  const int tid = threadIdx.x;
  const int lane = tid & 63;
  const int wave = tid >> 6;
  const int wr = wave >> 1, wc = wave & 1;
  const int lhi = lane >> 4, llo = lane & 15;

  for (int kt = 0; kt < KD / 64; ++kt) {
    __syncthreads();
    // stage A tile: 1024 16B chunks; chunk c -> LDS byte c*16.
    // stored chunk scol holds data chunk scol^(row&7)  (read-side XOR inverse)
#pragma unroll
    for (int i = 0; i < 4; ++i) {
      int c = i * 256 + wave * 64 + lane;
      int row = c >> 3, scol = c & 7;
      int dcol = scol ^ (row & 7);
      gload16(A + (size_t)(m0 + row) * KD + kt * 64 + dcol * 8,
              sA + (i * 256 + wave * 64) * 8);
    }
#pragma unroll
    for (int i = 0; i < 4; ++i) {
      int c = i * 256 + wave * 64 + lane;
      int row = c >> 3, scol = c & 7;
      int dcol = scol ^ (row & 7);
      gload16(Bt + (size_t)(n0 + row) * KD + kt * 64 + dcol * 8,
              sB + (i * 256 + wave * 64) * 8);
    }
    __syncthreads();  // compiler drains vmcnt(0) here -> tile ready
#pragma unroll
    for (int ks = 0; ks < 2; ++ks) {
      const int kb = ks * 64 + lhi * 16;
      bf16x8 af[4], bfr[4];
#pragma unroll
      for (int mi = 0; mi < 4; ++mi) {
        int row = wr * 64 + mi * 16 + llo;
        af[mi] = *(const bf16x8*)((char*)sA + row * 128 + (kb ^ ((row & 7) << 4)));
      }
#pragma unroll
      for (int ni = 0; ni < 4; ++ni) {
        int row = wc * 64 + ni * 16 + llo;
        bfr[ni] = *(const bf16x8*)((char*)sB + row * 128 + (kb ^ ((row & 7) << 4)));
      }
#pragma unroll
      for (int mi = 0; mi < 4; ++mi)
#pragma unroll
        for (int ni = 0; ni < 4; ++ni)
          acc[mi][ni] = mfma16(af[mi], bfr[ni], acc[mi][ni]);
    }
  }
}

// ---------------------------------------------------------------------------
// Projections: z=0 Q, z=1 K -> (b,h,s,dk) bf16; z=2 V -> (b,h,dv,s) bf16
// (transposed for PV); z=3 gate -> silu -> (b,s,hid) bf16.
// ---------------------------------------------------------------------------
__global__ __launch_bounds__(256) void proj_kernel(
    const u16* __restrict__ xb, const u16* __restrict__ wtBase,
    const float* __restrict__ bq, const float* __restrict__ bk,
    const float* __restrict__ bv, const float* __restrict__ bg,
    u16* __restrict__ qb, u16* __restrict__ kb,
    u16* __restrict__ vtb, u16* __restrict__ gb)
{
  __shared__ u16 sA[128 * 64];
  __shared__ u16 sB[128 * 64];
  const int z = blockIdx.z;
  const u16* Bt = wtBase + (size_t)z * (size_t)KD * HID;
  f32x4 acc[4][4];
  const f32x4 zero = {0.f, 0.f, 0.f, 0.f};
#pragma unroll
  for (int mi = 0; mi < 4; ++mi)
#pragma unroll
    for (int ni = 0; ni < 4; ++ni) acc[mi][ni] = zero;

  const int m0 = blockIdx.x * 128, n0 = blockIdx.y * 128;
  gemm_core(xb, Bt, m0, n0, sA, sB, acc);

  const float* bias = (z == 0) ? bq : (z == 1) ? bk : (z == 2) ? bv : bg;
  const int lane = threadIdx.x & 63, wave = threadIdx.x >> 6;
  const int wr = wave >> 1, wc = wave & 1;
  const int lhi = lane >> 4, llo = lane & 15;
#pragma unroll
  for (int mi = 0; mi < 4; ++mi) {
#pragma unroll
    for (int ni = 0; ni < 4; ++ni) {
      int row0 = m0 + wr * 64 + mi * 16 + lhi * 4;
      int n = n0 + wc * 64 + ni * 16 + llo;
      float bsn = bias[n];
      if (z == 2) {
        int b = row0 >> 11, s0 = row0 & (SS - 1);
        int h = n >> 7, j = n & 127;
        ushort4 hv;
        hv.x = f2bf(acc[mi][ni][0] + bsn);
        hv.y = f2bf(acc[mi][ni][1] + bsn);
        hv.z = f2bf(acc[mi][ni][2] + bsn);
        hv.w = f2bf(acc[mi][ni][3] + bsn);
        *(ushort4*)(vtb + ((size_t)((b * NH + h) * DV + j)) * SS + s0) = hv;
      } else if (z == 3) {
#pragma unroll
        for (int r = 0; r < 4; ++r) {
          int m = row0 + r;
          float c = acc[mi][ni][r] + bsn;
          float sg = c / (1.0f + expf(-c));
          gb[(size_t)m * HID + n] = f2bf(sg);
        }
      } else {
        u16* dst = (z == 0) ? qb : kb;
#pragma unroll
        for (int r = 0; r < 4; ++r) {
          int m = row0 + r;
          int b = m >> 11, s = m & (SS - 1);
          int h = n >> 7, j = n & 127;
          dst[((size_t)((b * NH + h) * SS + s)) * DK + j] = f2bf(acc[mi][ni][r] + bsn);
        }
      }
    }
  }
}

// ---------------------------------------------------------------------------
// Retention: per (b,h, 128-row q tile). Stream 64-row K/V tiles with decay
// mask gamma^(n-m) applied as gamma^n * gamma^-m. Outputs fp32 ret (b,h,s,dv)
// and atomic per-(b,h) sum/sumsq for GroupNorm.
// K/V staged via global_load_lds (inverse-swizzled source, swizzled reads).
// ---------------------------------------------------------------------------
__global__ __launch_bounds__(256) void retention_kernel(
    const u16* __restrict__ qb, const u16* __restrict__ kb,
    const u16* __restrict__ vtb, const float* __restrict__ gamma,
    float* __restrict__ ret, float* __restrict__ stats)
{
  __shared__ u16 sK[64 * 128];   // [m 0..63][k 0..127], 256B rows, swz (row&15)<<4
  __shared__ u16 sV[128 * 64];   // [dv 0..127][m 0..63], 128B rows, swz (row&7)<<4
  __shared__ u16 sP[4][32 * 64]; // per-wave P, 128B rows, swz (row&7)<<4
  __shared__ float red[8];

  const int bh = blockIdx.y;
  const int n0 = blockIdx.x * 128;
  const int h = bh & (NH - 1);
  const float lg2 = log2f(gamma[h]);

  const int tid = threadIdx.x, lane = tid & 63, wave = tid >> 6;
  const int lhi = lane >> 4, llo = lane & 15;
  const int qrow = n0 + wave * 32;

  // Q fragments in registers (reused across all m tiles)
  const u16* qbase = qb + ((size_t)bh * SS + qrow) * DK;
  bf16x8 aq[2][4];
#pragma unroll
  for (int mi = 0; mi < 2; ++mi)
#pragma unroll
    for (int ks = 0; ks < 4; ++ks)
      aq[mi][ks] = *(const bf16x8*)(qbase + (size_t)(mi * 16 + llo) * DK + ks * 32 + lhi * 8);

  float rdec[2][4];
#pragma unroll
  for (int mi = 0; mi < 2; ++mi)
#pragma unroll
    for (int r = 0; r < 4; ++r)
      rdec[mi][r] = exp2f(lg2 * (float)(qrow + mi * 16 + lhi * 4 + r));

  const f32x4 zero = {0.f, 0.f, 0.f, 0.f};
  f32x4 oacc[2][8];
#pragma unroll
  for (int mi = 0; mi < 2; ++mi)
#pragma unroll
    for (int nj = 0; nj < 8; ++nj) oacc[mi][nj] = zero;

  const u16* kbase = kb + (size_t)bh * SS * DK;
  const u16* vbase = vtb + (size_t)bh * DV * SS;
  const int mtiles = n0 / 64 + 2;

  for (int mt = 0; mt < mtiles; ++mt) {
    const int m0 = mt * 64;
    __syncthreads();
    // stage K tile (64 x 128 bf16): 1024 chunks, 256B rows, swz (row&15)
#pragma unroll
    for (int i = 0; i < 4; ++i) {
      int c = i * 256 + wave * 64 + lane;
      int row = c >> 4, scol = c & 15;
      int dcol = scol ^ (row & 15);
      gload16(kbase + (size_t)(m0 + row) * DK + dcol * 8,
              sK + (i * 256 + wave * 64) * 8);
    }
    // stage Vt tile (128 x 64 bf16): 1024 chunks, 128B rows, swz (row&7)
#pragma unroll
    for (int i = 0; i < 4; ++i) {
      int c = i * 256 + wave * 64 + lane;
      int row = c >> 3, scol = c & 7;
      int dcol = scol ^ (row & 7);
      gload16(vbase + (size_t)row * SS + m0 + dcol * 8,
              sV + (i * 256 + wave * 64) * 8);
    }
    __syncthreads();

    // QK^T
    f32x4 sacc[2][4];
#pragma unroll
    for (int mi = 0; mi < 2; ++mi)
#pragma unroll
      for (int ni = 0; ni < 4; ++ni) sacc[mi][ni] = zero;
#pragma unroll
    for (int ks = 0; ks < 4; ++ks) {
      const int kbyte = ks * 64 + lhi * 16;
      bf16x8 bk_[4];
#pragma unroll
      for (int ni = 0; ni < 4; ++ni) {
        int row = ni * 16 + llo;
        bk_[ni] = *(const bf16x8*)((char*)sK + row * 256 + (kbyte ^ ((row & 15) << 4)));
      }
#pragma unroll
      for (int mi = 0; mi < 2; ++mi)
#pragma unroll
        for (int ni = 0; ni < 4; ++ni)
          sacc[mi][ni] = mfma16(aq[mi][ks], bk_[ni], sacc[mi][ni]);
    }

    // decay + causal mask + bf16 P into per-wave LDS
    float cfac[4];
#pragma unroll
    for (int ni = 0; ni < 4; ++ni)
      cfac[ni] = exp2f(-lg2 * (float)(m0 + ni * 16 + llo));
    const bool masked = (m0 + 63 > qrow);
    char* myP = (char*)&sP[wave][0];
#pragma unroll
    for (int mi = 0; mi < 2; ++mi) {
#pragma unroll
      for (int ni = 0; ni < 4; ++ni) {
#pragma unroll
        for (int r = 0; r < 4; ++r) {
          int prow = mi * 16 + lhi * 4 + r;
          int pcol = ni * 16 + llo;
          float w = rdec[mi][r] * cfac[ni];
          if (masked && (qrow + prow < m0 + pcol)) w = 0.0f;
          float p = sacc[mi][ni][r] * w;
          *(u16*)(myP + prow * 128 + ((pcol * 2) ^ ((prow & 7) << 4))) = f2bf(p);
        }
      }
    }

    // PV (same-wave LDS write->read; compiler inserts lgkmcnt)
#pragma unroll
    for (int ks2 = 0; ks2 < 2; ++ks2) {
      const int kbyte = ks2 * 64 + lhi * 16;
      bf16x8 pa[2];
#pragma unroll
      for (int mi = 0; mi < 2; ++mi) {
        int row = mi * 16 + llo;
        pa[mi] = *(const bf16x8*)(myP + row * 128 + (kbyte ^ ((row & 7) << 4)));
      }
#pragma unroll
      for (int nj = 0; nj < 8; ++nj) {
        int row = nj * 16 + llo;
        bf16x8 vb = *(const bf16x8*)((char*)sV + row * 128 + (kbyte ^ ((row & 7) << 4)));
#pragma unroll
        for (int mi = 0; mi < 2; ++mi)
          oacc[mi][nj] = mfma16(pa[mi], vb, oacc[mi][nj]);
      }
    }
  }

  // write ret + local stats
  float lsum = 0.f, lsq = 0.f;
  float* rbase = ret + ((size_t)bh * SS + qrow) * DV;
#pragma unroll
  for (int mi = 0; mi < 2; ++mi) {
#pragma unroll
    for (int nj = 0; nj < 8; ++nj) {
      int prow0 = mi * 16 + lhi * 4;
      int j = nj * 16 + llo;
#pragma unroll
      for (int r = 0; r < 4; ++r) {
        float v = oacc[mi][nj][r];
        rbase[(size_t)(prow0 + r) * DV + j] = v;
        lsum += v; lsq += v * v;
      }
    }
  }
#pragma unroll
  for (int off = 32; off > 0; off >>= 1) {
    lsum += __shfl_down(lsum, off, 64);
    lsq  += __shfl_down(lsq,  off, 64);
  }
  if (lane == 0) { red[wave * 2] = lsum; red[wave * 2 + 1] = lsq; }
  __syncthreads();
  if (tid == 0) {
    float s = red[0] + red[2] + red[4] + red[6];
    float q = red[1] + red[3] + red[5] + red[7];
    atomicAdd(&stats[bh * 2], s);
    atomicAdd(&stats[bh * 2 + 1], q);
  }
}

// ---------------------------------------------------------------------------
// GroupNorm (per b,head over s,dv) * gate -> A2 bf16 (b,s,hid)
// ---------------------------------------------------------------------------
__global__ __launch_bounds__(256) void normgate_kernel(
    const float* __restrict__ ret, const u16* __restrict__ gb,
    const float* __restrict__ stats, const float* __restrict__ gn_w,
    const float* __restrict__ gn_b, u16* __restrict__ a2)
{
  const int idx4 = (blockIdx.x * 256 + threadIdx.x) * 4;
  const int bh = idx4 >> 18;              // / (S*DV)
  const int rem = idx4 & (SS * DV - 1);
  const int s = rem >> 7;
  const int dv = rem & (DV - 1);
  const float inv = 1.0f / (float)(SS * DV);
  float mean = stats[bh * 2] * inv;
  float var = stats[bh * 2 + 1] * inv - mean * mean;
  float rstd = rsqrtf(var + 1e-5f);
  const int b = bh >> 4, h = bh & (NH - 1);
  const int hd = h * DV + dv;
  float4 rv = *(const float4*)(ret + idx4);
  float4 w4 = *(const float4*)(gn_w + hd);
  float4 b4 = *(const float4*)(gn_b + hd);
  size_t gidx = ((size_t)(b * SS + s)) * HID + hd;
  ushort4 g4 = *(const ushort4*)(gb + gidx);
  ushort4 o;
  o.x = f2bf(bf2f(g4.x) * ((rv.x - mean) * rstd * w4.x + b4.x));
  o.y = f2bf(bf2f(g4.y) * ((rv.y - mean) * rstd * w4.y + b4.y));
  o.z = f2bf(bf2f(g4.z) * ((rv.z - mean) * rstd * w4.z + b4.z));
  o.w = f2bf(bf2f(g4.w) * ((rv.w - mean) * rstd * w4.w + b4.w));
  *(ushort4*)(a2 + gidx) = o;
}

// ---------------------------------------------------------------------------
// Final GEMM: out = A2 @ wo + bo, fp32 out
// ---------------------------------------------------------------------------
__global__ __launch_bounds__(256) void final_kernel(
    const u16* __restrict__ a2, const u16* __restrict__ woT,
    const float* __restrict__ bo, float* __restrict__ out)
{
  __shared__ u16 sA[128 * 64];
  __shared__ u16 sB[128 * 64];
  f32x4 acc[4][4];
  const f32x4 zero = {0.f, 0.f, 0.f, 0.f};
#pragma unroll
  for (int mi = 0; mi < 4; ++mi)
#pragma unroll
    for (int ni = 0; ni < 4; ++ni) acc[mi][ni] = zero;

  const int m0 = blockIdx.x * 128, n0 = blockIdx.y * 128;
  gemm_core(a2, woT, m0, n0, sA, sB, acc);

  const int lane = threadIdx.x & 63, wave = threadIdx.x >> 6;
  const int wr = wave >> 1, wc = wave & 1;
  const int lhi = lane >> 4, llo = lane & 15;
#pragma unroll
  for (int mi = 0; mi < 4; ++mi) {
#pragma unroll
    for (int ni = 0; ni < 4; ++ni) {
      int row0 = m0 + wr * 64 + mi * 16 + lhi * 4;
      int n = n0 + wc * 64 + ni * 16 + llo;
      float bn = bo[n];
#pragma unroll
      for (int r = 0; r < 4; ++r)
        out[(size_t)(row0 + r) * HID + n] = acc[mi][ni][r] + bn;
    }
  }
}

// ---------------------------------------------------------------------------
extern "C" void kernel_launch(void* const* d_in, const int* in_sizes, int n_in,
                              void* d_out, int out_size, void* d_ws, size_t ws_size,
                              hipStream_t stream) {
  const float* x    = (const float*)d_in[0];
  const float* wq   = (const float*)d_in[1];
  const float* bq   = (const float*)d_in[2];
  const float* wk   = (const float*)d_in[3];
  const float* bk   = (const float*)d_in[4];
  const float* wv   = (const float*)d_in[5];
  const float* bv   = (const float*)d_in[6];
  const float* wg   = (const float*)d_in[7];
  const float* bg   = (const float*)d_in[8];
  const float* wo   = (const float*)d_in[9];
  const float* bo   = (const float*)d_in[10];
  const float* gn_w = (const float*)d_in[11];
  const float* gn_b = (const float*)d_in[12];
  const float* gam  = (const float*)d_in[13];

  char* ws = (char*)d_ws;
  // layout (bytes):
  u16* wT    = (u16*)(ws);                  // 5 * 8,388,608   = 41,943,040
  u16* qb    = (u16*)(ws + 41943040);       // 16,777,216
  u16* kbuf  = (u16*)(ws + 58720256);       // 16,777,216
  u16* vtb   = (u16*)(ws + 75497472);       // 16,777,216
  u16* gb    = (u16*)(ws + 92274688);       // 16,777,216
  float* ret = (float*)(ws + 109051904);    // 33,554,432
  float* st  = (float*)(ws + 142606336);    // 256
  u16* a2    = qb;                          // reuse (qb dead after retention)
  u16* xb    = (u16*)ret;                   // reuse (xb dead before retention writes ret)

  hipMemsetAsync(st, 0, 256, stream);
  castx_kernel<<<4096, 256, 0, stream>>>(x, xb);
  wtrans_kernel<<<dim3(64, 64, 5), dim3(32, 8), 0, stream>>>(wq, wk, wv, wg, wo, wT);
  proj_kernel<<<dim3(32, 16, 4), 256, 0, stream>>>(xb, wT, bq, bk, bv, bg, qb, kbuf, vtb, gb);
  retention_kernel<<<dim3(16, 32), 256, 0, stream>>>(qb, kbuf, vtb, gam, ret, st);
  normgate_kernel<<<16384, 256, 0, stream>>>(ret, gb, st, gn_w, gn_b, a2);
  final_kernel<<<dim3(32, 16), 256, 0, stream>>>(a2, wT + (size_t)4 * KD * HID, bo, (float*)d_out);
}

// Round 3
// 552.922 us; speedup vs baseline: 1.0972x; 1.0051x over previous
//
#include <hip/hip_runtime.h>
#include <cstdint>
#include <cstddef>

#define DEVI __device__ __forceinline__

typedef unsigned short u16;
typedef __bf16 bf16_t;
typedef bf16_t bf16x8 __attribute__((ext_vector_type(8)));
typedef float f32x4 __attribute__((ext_vector_type(4)));

// problem sizes (fixed)
constexpr int BB = 2, SS = 2048, HID = 2048, NH = 16, DK = 128, DV = 128;
constexpr int KD = HID;      // 2048 inner dim

DEVI u16 f2bf(float f) {
  union { float f; uint32_t u; } v; v.f = f;
  uint32_t u = v.u;
  uint32_t r = u + 0x7FFFu + ((u >> 16) & 1u);  // RNE
  return (u16)(r >> 16);
}
DEVI float bf2f(u16 h) {
  union { uint32_t u; float f; } v; v.u = ((uint32_t)h) << 16;
  return v.f;
}
DEVI f32x4 mfma16(bf16x8 a, bf16x8 b, f32x4 c) {
  return __builtin_amdgcn_mfma_f32_16x16x32_bf16(a, b, c, 0, 0, 0);
}
// async global->LDS, 16B per lane. LDS dest = wave-uniform base + lane*16.
DEVI void gload16(const u16* g, u16* l) {
  __builtin_amdgcn_global_load_lds(
      (const __attribute__((address_space(1))) uint32_t*)g,
      (__attribute__((address_space(3))) uint32_t*)l, 16, 0, 0);
}

// ---------------------------------------------------------------------------
// x fp32 -> bf16 (pre-cast so GEMM A-staging is pure global_load_lds)
// ---------------------------------------------------------------------------
__global__ __launch_bounds__(256) void castx_kernel(
    const float* __restrict__ x, u16* __restrict__ xb)
{
  size_t i = ((size_t)blockIdx.x * 256 + threadIdx.x) * 8;
  float4 a = *(const float4*)(x + i);
  float4 b = *(const float4*)(x + i + 4);
  ushort4 lo, hi;
  lo.x = f2bf(a.x); lo.y = f2bf(a.y); lo.z = f2bf(a.z); lo.w = f2bf(a.w);
  hi.x = f2bf(b.x); hi.y = f2bf(b.y); hi.z = f2bf(b.z); hi.w = f2bf(b.w);
  *(ushort4*)(xb + i) = lo;
  *(ushort4*)(xb + i + 4) = hi;
}

// ---------------------------------------------------------------------------
// Weight transpose + cast: W[k][n] fp32 -> WT[n][k] bf16  (NT-GEMM B operand)
// ---------------------------------------------------------------------------
__global__ __launch_bounds__(256) void wtrans_kernel(
    const float* __restrict__ wq, const float* __restrict__ wk,
    const float* __restrict__ wv, const float* __restrict__ wg,
    const float* __restrict__ wo, u16* __restrict__ wt)
{
  __shared__ float t[32][33];
  const float* srcs[5] = {wq, wk, wv, wg, wo};
  const float* W = srcs[blockIdx.z];
  u16* dst = wt + (size_t)blockIdx.z * (size_t)KD * HID;
  int tx = threadIdx.x, ty = threadIdx.y;
  int c0 = blockIdx.x * 32, r0 = blockIdx.y * 32;
#pragma unroll
  for (int i = 0; i < 4; ++i)
    t[ty + i * 8][tx] = W[(size_t)(r0 + ty + i * 8) * HID + c0 + tx];
  __syncthreads();
#pragma unroll
  for (int i = 0; i < 4; ++i) {
    int n = c0 + ty + i * 8;
    int k = r0 + tx;
    dst[(size_t)n * KD + k] = f2bf(t[tx][ty + i * 8]);
  }
}

// ---------------------------------------------------------------------------
// 256x256 GEMM core, BK=64, 8 waves (2M x 4N), 2-phase LDS double-buffer.
// Staging via global_load_lds w16 (linear LDS dest, inverse-swizzled source);
// reads via swizzled ds_read_b128 (conflict-free). LDS 128 KiB.
// Wave wr=wave>>2 owns rows wr*128..+127; wc=wave&3 owns cols wc*64..+63.
// ---------------------------------------------------------------------------
DEVI void stage256(const u16* __restrict__ A, const u16* __restrict__ Bt,
                   int m0, int n0, int kt, u16* sa, u16* sb, int tid)
{
#pragma unroll
  for (int i = 0; i < 4; ++i) {            // A: 256x64 bf16 = 2048 16B chunks
    int c = i * 512 + tid;
    int row = c >> 3, scol = c & 7, dcol = scol ^ (row & 7);
    gload16(A + (size_t)(m0 + row) * KD + kt * 64 + dcol * 8, sa + c * 8);
  }
#pragma unroll
  for (int i = 0; i < 4; ++i) {            // B: 256x64
    int c = i * 512 + tid;
    int row = c >> 3, scol = c & 7, dcol = scol ^ (row & 7);
    gload16(Bt + (size_t)(n0 + row) * KD + kt * 64 + dcol * 8, sb + c * 8);
  }
}

DEVI void gemm256(const u16* __restrict__ A, const u16* __restrict__ Bt,
                  int m0, int n0, char* smem, f32x4 (&acc)[8][4])
{
  const int tid = threadIdx.x, lane = tid & 63, wave = tid >> 6;
  const int wr = wave >> 2, wc = wave & 3;
  const int lhi = lane >> 4, llo = lane & 15;

  stage256(A, Bt, m0, n0, 0, (u16*)smem, (u16*)(smem + 65536), tid);
  asm volatile("s_waitcnt vmcnt(0)" ::: "memory");
  __syncthreads();

  for (int kt = 0; kt < KD / 64; ++kt) {
    char* cA = smem + (kt & 1) * 32768;
    char* cB = smem + 65536 + (kt & 1) * 32768;
    if (kt + 1 < KD / 64) {
      u16* nA = (u16*)(smem + ((kt + 1) & 1) * 32768);
      u16* nB = (u16*)(smem + 65536 + ((kt + 1) & 1) * 32768);
      stage256(A, Bt, m0, n0, kt + 1, nA, nB, tid);
    }
    __builtin_amdgcn_s_setprio(1);
#pragma unroll
    for (int ks = 0; ks < 2; ++ks) {
      const int kb = ks * 64 + lhi * 16;
      bf16x8 bfr[4];
#pragma unroll
      for (int ni = 0; ni < 4; ++ni) {
        int row = wc * 64 + ni * 16 + llo;
        bfr[ni] = *(const bf16x8*)(cB + row * 128 + (kb ^ ((row & 7) << 4)));
      }
#pragma unroll
      for (int mi = 0; mi < 8; ++mi) {
        int row = wr * 128 + mi * 16 + llo;
        bf16x8 af = *(const bf16x8*)(cA + row * 128 + (kb ^ ((row & 7) << 4)));
#pragma unroll
        for (int ni = 0; ni < 4; ++ni)
          acc[mi][ni] = mfma16(af, bfr[ni], acc[mi][ni]);
      }
    }
    __builtin_amdgcn_s_setprio(0);
    asm volatile("s_waitcnt vmcnt(0)" ::: "memory");
    __syncthreads();
  }
}

// ---------------------------------------------------------------------------
// Projections: z=0 Q, z=1 K -> (b,h,s,dk) bf16; z=2 V -> (b,h,dv,s) bf16
// (transposed for PV); z=3 gate -> silu -> (b,s,hid) bf16.
// z!=2 use an LDS-bounce epilogue: acc -> LDS (swizzled, conflict-free)
// -> 16B vector global stores.
// ---------------------------------------------------------------------------
__global__ __launch_bounds__(512, 2) void proj_kernel(
    const u16* __restrict__ xb, const u16* __restrict__ wtBase,
    const float* __restrict__ bq, const float* __restrict__ bk,
    const float* __restrict__ bv, const float* __restrict__ bg,
    u16* __restrict__ qb, u16* __restrict__ kb,
    u16* __restrict__ vtb, u16* __restrict__ gb)
{
  __shared__ __align__(16) char smem[131072];
  const int z = blockIdx.z;
  const u16* Bt = wtBase + (size_t)z * (size_t)KD * HID;
  f32x4 acc[8][4];
  const f32x4 zero = {0.f, 0.f, 0.f, 0.f};
#pragma unroll
  for (int mi = 0; mi < 8; ++mi)
#pragma unroll
    for (int ni = 0; ni < 4; ++ni) acc[mi][ni] = zero;

  const int m0 = blockIdx.x * 256, n0 = blockIdx.y * 256;
  gemm256(xb, Bt, m0, n0, smem, acc);

  const int tid = threadIdx.x, lane = tid & 63, wave = tid >> 6;
  const int wr = wave >> 2, wc = wave & 3;
  const int lhi = lane >> 4, llo = lane & 15;
  const float* bias = (z == 0) ? bq : (z == 1) ? bk : (z == 2) ? bv : bg;

  if (z == 2) {
    // direct transposed stores: pack r=0..3 (consecutive s) as ushort4
#pragma unroll
    for (int mi = 0; mi < 8; ++mi) {
#pragma unroll
      for (int ni = 0; ni < 4; ++ni) {
        int row0 = m0 + wr * 128 + mi * 16 + lhi * 4;
        int n = n0 + wc * 64 + ni * 16 + llo;
        float bsn = bias[n];
        int b = row0 >> 11, s0 = row0 & (SS - 1);
        int h = n >> 7, j = n & 127;
        ushort4 hv;
        hv.x = f2bf(acc[mi][ni][0] + bsn);
        hv.y = f2bf(acc[mi][ni][1] + bsn);
        hv.z = f2bf(acc[mi][ni][2] + bsn);
        hv.w = f2bf(acc[mi][ni][3] + bsn);
        *(ushort4*)(vtb + ((size_t)((b * NH + h) * DV + j)) * SS + s0) = hv;
      }
    }
  } else {
    // LDS-bounce: Lb[row][col^(((row>>2)&3)<<4)] u16, 256x256
    u16* Lb = (u16*)smem;
#pragma unroll
    for (int mi = 0; mi < 8; ++mi) {
#pragma unroll
      for (int ni = 0; ni < 4; ++ni) {
        int colL = wc * 64 + ni * 16 + llo;
        float bsn = bias[n0 + colL];
#pragma unroll
        for (int r = 0; r < 4; ++r) {
          int rowL = wr * 128 + mi * 16 + lhi * 4 + r;
          float c = acc[mi][ni][r] + bsn;
          if (z == 3) c = c / (1.0f + expf(-c));
          Lb[rowL * 256 + (colL ^ (((rowL >> 2) & 3) << 4))] = f2bf(c);
        }
      }
    }
    __syncthreads();
    int rr = tid & 255, chh = tid >> 8;
    int m = m0 + rr, b = m >> 11, s = m & (SS - 1);
    int swz = ((rr >> 2) & 3) << 4;
#pragma unroll
    for (int jj = 0; jj < 16; ++jj) {
      int c0 = chh * 128 + jj * 8;
      uint4 v = *(const uint4*)&Lb[rr * 256 + (c0 ^ swz)];
      int n = n0 + c0;
      if (z == 3) {
        *(uint4*)(gb + (size_t)m * HID + n) = v;
      } else {
        int h = n >> 7, j2 = n & 127;
        u16* dst = (z == 0) ? qb : kb;
        *(uint4*)(dst + ((size_t)((b * NH + h) * SS + s)) * DK + j2) = v;
      }
    }
  }
}

// ---------------------------------------------------------------------------
// Retention: per (b,h, 128-row q tile). Stream 64-row K/V tiles with decay
// mask gamma^(n-m) = gamma^n * gamma^-m. 2-phase double-buffered K/V staging.
// Outputs fp32 ret (b,h,s,dv) + atomic per-(b,h) sum/sumsq for GroupNorm.
// ---------------------------------------------------------------------------
__global__ __launch_bounds__(256) void retention_kernel(
    const u16* __restrict__ qb, const u16* __restrict__ kb,
    const u16* __restrict__ vtb, const float* __restrict__ gamma,
    float* __restrict__ ret, float* __restrict__ stats)
{
  // LDS: sK dbuf 2x16KB @0, sV dbuf 2x16KB @32768, sP 4x4KB @65536 = 80KB
  __shared__ __align__(16) char smemR[81920];
  __shared__ float red[8];

  const int bh = blockIdx.y;
  const int n0 = blockIdx.x * 128;
  const int h = bh & (NH - 1);
  const float lg2 = log2f(gamma[h]);

  const int tid = threadIdx.x, lane = tid & 63, wave = tid >> 6;
  const int lhi = lane >> 4, llo = lane & 15;
  const int qrow = n0 + wave * 32;

  // Q fragments in registers (reused across all m tiles)
  const u16* qbase = qb + ((size_t)bh * SS + qrow) * DK;
  bf16x8 aq[2][4];
#pragma unroll
  for (int mi = 0; mi < 2; ++mi)
#pragma unroll
    for (int ks = 0; ks < 4; ++ks)
      aq[mi][ks] = *(const bf16x8*)(qbase + (size_t)(mi * 16 + llo) * DK + ks * 32 + lhi * 8);

  float rdec[2][4];
#pragma unroll
  for (int mi = 0; mi < 2; ++mi)
#pragma unroll
    for (int r = 0; r < 4; ++r)
      rdec[mi][r] = exp2f(lg2 * (float)(qrow + mi * 16 + lhi * 4 + r));

  const f32x4 zero = {0.f, 0.f, 0.f, 0.f};
  f32x4 oacc[2][8];
#pragma unroll
  for (int mi = 0; mi < 2; ++mi)
#pragma unroll
    for (int nj = 0; nj < 8; ++nj) oacc[mi][nj] = zero;

  const u16* kbase = kb + (size_t)bh * SS * DK;
  const u16* vbase = vtb + (size_t)bh * DV * SS;
  const int mtiles = n0 / 64 + 2;

  auto stageKV = [&](int mbase, u16* sk, u16* sv) {
#pragma unroll
    for (int i = 0; i < 4; ++i) {   // K: 64x128, 256B rows, swz (row&15)<<4
      int c = i * 256 + tid;
      int row = c >> 4, scol = c & 15, dcol = scol ^ (row & 15);
      gload16(kbase + (size_t)(mbase + row) * DK + dcol * 8, sk + c * 8);
    }
#pragma unroll
    for (int i = 0; i < 4; ++i) {   // Vt: 128x64, 128B rows, swz (row&7)<<4
      int c = i * 256 + tid;
      int row = c >> 3, scol = c & 7, dcol = scol ^ (row & 7);
      gload16(vbase + (size_t)row * SS + mbase + dcol * 8, sv + c * 8);
    }
  };

  stageKV(0, (u16*)smemR, (u16*)(smemR + 32768));
  asm volatile("s_waitcnt vmcnt(0)" ::: "memory");
  __syncthreads();

  for (int mt = 0; mt < mtiles; ++mt) {
    const int m0 = mt * 64;
    char* cK = smemR + (mt & 1) * 16384;
    char* cV = smemR + 32768 + (mt & 1) * 16384;
    if (mt + 1 < mtiles)
      stageKV(m0 + 64, (u16*)(smemR + ((mt + 1) & 1) * 16384),
              (u16*)(smemR + 32768 + ((mt + 1) & 1) * 16384));

    // QK^T
    f32x4 sacc[2][4];
#pragma unroll
    for (int mi = 0; mi < 2; ++mi)
#pragma unroll
      for (int ni = 0; ni < 4; ++ni) sacc[mi][ni] = zero;
    __builtin_amdgcn_s_setprio(1);
#pragma unroll
    for (int ks = 0; ks < 4; ++ks) {
      const int kbyte = ks * 64 + lhi * 16;
      bf16x8 bk_[4];
#pragma unroll
      for (int ni = 0; ni < 4; ++ni) {
        int row = ni * 16 + llo;
        bk_[ni] = *(const bf16x8*)(cK + row * 256 + (kbyte ^ ((row & 15) << 4)));
      }
#pragma unroll
      for (int mi = 0; mi < 2; ++mi)
#pragma unroll
        for (int ni = 0; ni < 4; ++ni)
          sacc[mi][ni] = mfma16(aq[mi][ks], bk_[ni], sacc[mi][ni]);
    }
    __builtin_amdgcn_s_setprio(0);

    // decay + causal mask + bf16 P into per-wave LDS
    float cfac[4];
#pragma unroll
    for (int ni = 0; ni < 4; ++ni)
      cfac[ni] = exp2f(-lg2 * (float)(m0 + ni * 16 + llo));
    const bool masked = (m0 + 63 > qrow);
    char* myP = smemR + 65536 + wave * 4096;
#pragma unroll
    for (int mi = 0; mi < 2; ++mi) {
#pragma unroll
      for (int ni = 0; ni < 4; ++ni) {
#pragma unroll
        for (int r = 0; r < 4; ++r) {
          int prow = mi * 16 + lhi * 4 + r;
          int pcol = ni * 16 + llo;
          float w = rdec[mi][r] * cfac[ni];
          if (masked && (qrow + prow < m0 + pcol)) w = 0.0f;
          float p = sacc[mi][ni][r] * w;
          *(u16*)(myP + prow * 128 + ((pcol * 2) ^ ((prow & 7) << 4))) = f2bf(p);
        }
      }
    }

    // PV (same-wave LDS write->read; compiler inserts lgkmcnt)
    __builtin_amdgcn_s_setprio(1);
#pragma unroll
    for (int ks2 = 0; ks2 < 2; ++ks2) {
      const int kbyte = ks2 * 64 + lhi * 16;
      bf16x8 pa[2];
#pragma unroll
      for (int mi = 0; mi < 2; ++mi) {
        int row = mi * 16 + llo;
        pa[mi] = *(const bf16x8*)(myP + row * 128 + (kbyte ^ ((row & 7) << 4)));
      }
#pragma unroll
      for (int nj = 0; nj < 8; ++nj) {
        int row = nj * 16 + llo;
        bf16x8 vb = *(const bf16x8*)(cV + row * 128 + (kbyte ^ ((row & 7) << 4)));
#pragma unroll
        for (int mi = 0; mi < 2; ++mi)
          oacc[mi][nj] = mfma16(pa[mi], vb, oacc[mi][nj]);
      }
    }
    __builtin_amdgcn_s_setprio(0);
    asm volatile("s_waitcnt vmcnt(0)" ::: "memory");
    __syncthreads();
  }

  // write ret + local stats
  float lsum = 0.f, lsq = 0.f;
  float* rbase = ret + ((size_t)bh * SS + qrow) * DV;
#pragma unroll
  for (int mi = 0; mi < 2; ++mi) {
#pragma unroll
    for (int nj = 0; nj < 8; ++nj) {
      int prow0 = mi * 16 + lhi * 4;
      int j = nj * 16 + llo;
#pragma unroll
      for (int r = 0; r < 4; ++r) {
        float v = oacc[mi][nj][r];
        rbase[(size_t)(prow0 + r) * DV + j] = v;
        lsum += v; lsq += v * v;
      }
    }
  }
#pragma unroll
  for (int off = 32; off > 0; off >>= 1) {
    lsum += __shfl_down(lsum, off, 64);
    lsq  += __shfl_down(lsq,  off, 64);
  }
  if (lane == 0) { red[wave * 2] = lsum; red[wave * 2 + 1] = lsq; }
  __syncthreads();
  if (tid == 0) {
    float s = red[0] + red[2] + red[4] + red[6];
    float q = red[1] + red[3] + red[5] + red[7];
    atomicAdd(&stats[bh * 2], s);
    atomicAdd(&stats[bh * 2 + 1], q);
  }
}

// ---------------------------------------------------------------------------
// GroupNorm (per b,head over s,dv) * gate -> A2 bf16 (b,s,hid)
// ---------------------------------------------------------------------------
__global__ __launch_bounds__(256) void normgate_kernel(
    const float* __restrict__ ret, const u16* __restrict__ gb,
    const float* __restrict__ stats, const float* __restrict__ gn_w,
    const float* __restrict__ gn_b, u16* __restrict__ a2)
{
  const int idx4 = (blockIdx.x * 256 + threadIdx.x) * 4;
  const int bh = idx4 >> 18;              // / (S*DV)
  const int rem = idx4 & (SS * DV - 1);
  const int s = rem >> 7;
  const int dv = rem & (DV - 1);
  const float inv = 1.0f / (float)(SS * DV);
  float mean = stats[bh * 2] * inv;
  float var = stats[bh * 2 + 1] * inv - mean * mean;
  float rstd = rsqrtf(var + 1e-5f);
  const int b = bh >> 4, h = bh & (NH - 1);
  const int hd = h * DV + dv;
  float4 rv = *(const float4*)(ret + idx4);
  float4 w4 = *(const float4*)(gn_w + hd);
  float4 b4 = *(const float4*)(gn_b + hd);
  size_t gidx = ((size_t)(b * SS + s)) * HID + hd;
  ushort4 g4 = *(const ushort4*)(gb + gidx);
  ushort4 o;
  o.x = f2bf(bf2f(g4.x) * ((rv.x - mean) * rstd * w4.x + b4.x));
  o.y = f2bf(bf2f(g4.y) * ((rv.y - mean) * rstd * w4.y + b4.y));
  o.z = f2bf(bf2f(g4.z) * ((rv.z - mean) * rstd * w4.z + b4.z));
  o.w = f2bf(bf2f(g4.w) * ((rv.w - mean) * rstd * w4.w + b4.w));
  *(ushort4*)(a2 + gidx) = o;
}

// ---------------------------------------------------------------------------
// Final GEMM: out = A2 @ wo + bo, fp32 out. 256x256 core + 2-pass fp32
// LDS-bounce epilogue (float4 stores).
// ---------------------------------------------------------------------------
__global__ __launch_bounds__(512, 2) void final_kernel(
    const u16* __restrict__ a2, const u16* __restrict__ woT,
    const float* __restrict__ bo, float* __restrict__ out)
{
  __shared__ __align__(16) char smem[131072];
  f32x4 acc[8][4];
  const f32x4 zero = {0.f, 0.f, 0.f, 0.f};
#pragma unroll
  for (int mi = 0; mi < 8; ++mi)
#pragma unroll
    for (int ni = 0; ni < 4; ++ni) acc[mi][ni] = zero;

  const int m0 = blockIdx.x * 256, n0 = blockIdx.y * 256;
  gemm256(a2, woT, m0, n0, smem, acc);

  const int tid = threadIdx.x, lane = tid & 63, wave = tid >> 6;
  const int wr = wave >> 2, wc = wave & 3;
  const int lhi = lane >> 4, llo = lane & 15;
  float* Lf = (float*)smem;   // 256 x 128 fp32 per pass

#pragma unroll
  for (int pass = 0; pass < 2; ++pass) {
    if ((wc >> 1) == pass) {
#pragma unroll
      for (int mi = 0; mi < 8; ++mi) {
#pragma unroll
        for (int ni = 0; ni < 4; ++ni) {
          int colL = (wc & 1) * 64 + ni * 16 + llo;
          float bn = bo[n0 + pass * 128 + colL];
#pragma unroll
          for (int r = 0; r < 4; ++r) {
            int rowL = wr * 128 + mi * 16 + lhi * 4 + r;
            Lf[rowL * 128 + (colL ^ (((rowL >> 2) & 1) << 4))] =
                acc[mi][ni][r] + bn;
          }
        }
      }
    }
    __syncthreads();
    int rr = tid & 255, chh = tid >> 8;
    int m = m0 + rr;
    int swz = ((rr >> 2) & 1) << 4;
#pragma unroll
    for (int jj = 0; jj < 16; ++jj) {
      int c0 = chh * 64 + jj * 4;
      float4 v = *(const float4*)&Lf[rr * 128 + (c0 ^ swz)];
      *(float4*)(out + (size_t)m * HID + n0 + pass * 128 + c0) = v;
    }
    __syncthreads();
  }
}

// ---------------------------------------------------------------------------
extern "C" void kernel_launch(void* const* d_in, const int* in_sizes, int n_in,
                              void* d_out, int out_size, void* d_ws, size_t ws_size,
                              hipStream_t stream) {
  const float* x    = (const float*)d_in[0];
  const float* wq   = (const float*)d_in[1];
  const float* bq   = (const float*)d_in[2];
  const float* wk   = (const float*)d_in[3];
  const float* bk   = (const float*)d_in[4];
  const float* wv   = (const float*)d_in[5];
  const float* bv   = (const float*)d_in[6];
  const float* wg   = (const float*)d_in[7];
  const float* bg   = (const float*)d_in[8];
  const float* wo   = (const float*)d_in[9];
  const float* bo   = (const float*)d_in[10];
  const float* gn_w = (const float*)d_in[11];
  const float* gn_b = (const float*)d_in[12];
  const float* gam  = (const float*)d_in[13];

  char* ws = (char*)d_ws;
  // layout (bytes):
  u16* wT    = (u16*)(ws);                  // 5 * 8,388,608   = 41,943,040
  u16* qb    = (u16*)(ws + 41943040);       // 16,777,216
  u16* kbuf  = (u16*)(ws + 58720256);       // 16,777,216
  u16* vtb   = (u16*)(ws + 75497472);       // 16,777,216
  u16* gb    = (u16*)(ws + 92274688);       // 16,777,216
  float* ret = (float*)(ws + 109051904);    // 33,554,432
  float* st  = (float*)(ws + 142606336);    // 256
  u16* a2    = qb;                          // reuse (qb dead after retention)
  u16* xb    = (u16*)ret;                   // reuse (xb dead before retention writes ret)

  hipMemsetAsync(st, 0, 256, stream);
  castx_kernel<<<4096, 256, 0, stream>>>(x, xb);
  wtrans_kernel<<<dim3(64, 64, 5), dim3(32, 8), 0, stream>>>(wq, wk, wv, wg, wo, wT);
  proj_kernel<<<dim3(16, 8, 4), 512, 0, stream>>>(xb, wT, bq, bk, bv, bg, qb, kbuf, vtb, gb);
  retention_kernel<<<dim3(16, 32), 256, 0, stream>>>(qb, kbuf, vtb, gam, ret, st);
  normgate_kernel<<<16384, 256, 0, stream>>>(ret, gb, st, gn_w, gn_b, a2);
  final_kernel<<<dim3(16, 8), 512, 0, stream>>>(a2, wT + (size_t)4 * KD * HID, bo, (float*)d_out);
}

// Round 6
// 521.314 us; speedup vs baseline: 1.1638x; 1.0606x over previous
//
#include <hip/hip_runtime.h>
#include <cstdint>
#include <cstddef>

#define DEVI __device__ __forceinline__

typedef unsigned short u16;
typedef __bf16 bf16_t;
typedef bf16_t bf16x8 __attribute__((ext_vector_type(8)));
typedef float f32x4 __attribute__((ext_vector_type(4)));

// problem sizes (fixed)
constexpr int BB = 2, SS = 2048, HID = 2048, NH = 16, DK = 128, DV = 128;
constexpr int KD = HID;      // 2048 inner dim

DEVI u16 f2bf(float f) {
  union { float f; uint32_t u; } v; v.f = f;
  uint32_t u = v.u;
  uint32_t r = u + 0x7FFFu + ((u >> 16) & 1u);  // RNE
  return (u16)(r >> 16);
}
DEVI float bf2f(u16 h) {
  union { uint32_t u; float f; } v; v.u = ((uint32_t)h) << 16;
  return v.f;
}
DEVI f32x4 mfma16(bf16x8 a, bf16x8 b, f32x4 c) {
  return __builtin_amdgcn_mfma_f32_16x16x32_bf16(a, b, c, 0, 0, 0);
}
// async global->LDS, 16B per lane. LDS dest = wave-uniform base + lane*16.
DEVI void gload16(const u16* g, u16* l) {
  __builtin_amdgcn_global_load_lds(
      (const __attribute__((address_space(1))) uint32_t*)g,
      (__attribute__((address_space(3))) uint32_t*)l, 16, 0, 0);
}

#define WAITVM(N) asm volatile("s_waitcnt vmcnt(" #N ")" ::: "memory")

// ---------------------------------------------------------------------------
// x fp32 -> bf16 (pre-cast so GEMM A-staging is pure global_load_lds)
// ---------------------------------------------------------------------------
__global__ __launch_bounds__(256) void castx_kernel(
    const float* __restrict__ x, u16* __restrict__ xb)
{
  size_t i = ((size_t)blockIdx.x * 256 + threadIdx.x) * 8;
  float4 a = *(const float4*)(x + i);
  float4 b = *(const float4*)(x + i + 4);
  ushort4 lo, hi;
  lo.x = f2bf(a.x); lo.y = f2bf(a.y); lo.z = f2bf(a.z); lo.w = f2bf(a.w);
  hi.x = f2bf(b.x); hi.y = f2bf(b.y); hi.z = f2bf(b.z); hi.w = f2bf(b.w);
  *(ushort4*)(xb + i) = lo;
  *(ushort4*)(xb + i + 4) = hi;
}

// ---------------------------------------------------------------------------
// Weight transpose + cast: W[k][n] fp32 -> WT[n][k] bf16  (NT-GEMM B operand)
// ---------------------------------------------------------------------------
__global__ __launch_bounds__(256) void wtrans_kernel(
    const float* __restrict__ wq, const float* __restrict__ wk,
    const float* __restrict__ wv, const float* __restrict__ wg,
    const float* __restrict__ wo, u16* __restrict__ wt)
{
  __shared__ float t[32][33];
  const float* srcs[5] = {wq, wk, wv, wg, wo};
  const float* W = srcs[blockIdx.z];
  u16* dst = wt + (size_t)blockIdx.z * (size_t)KD * HID;
  int tx = threadIdx.x, ty = threadIdx.y;
  int c0 = blockIdx.x * 32, r0 = blockIdx.y * 32;
#pragma unroll
  for (int i = 0; i < 4; ++i)
    t[ty + i * 8][tx] = W[(size_t)(r0 + ty + i * 8) * HID + c0 + tx];
  __syncthreads();
#pragma unroll
  for (int i = 0; i < 4; ++i) {
    int n = c0 + ty + i * 8;
    int k = r0 + tx;
    dst[(size_t)n * KD + k] = f2bf(t[tx][ty + i * 8]);
  }
}

// ---------------------------------------------------------------------------
// Ring-buffer GEMM core: BK=32, 4 LDS slots per operand, counted vmcnt,
// raw s_barrier + sched_barrier(0). Batch for K-step kt staged at kt-3;
// at end of step kt each wave drains its own batch kt+1 (vmcnt(2*LPB)),
// then barrier => batch kt+1 globally visible. Loads never drain to 0
// in steady state (T4). LDS layout per slot: row pair r2=r>>1 holds
// 128B = [sub=r&1][col16 c' = c ^ (r2&3)] -> conflict-free ds_read_b128.
// ---------------------------------------------------------------------------
template<int BM, int BN>
DEVI void stage32(const u16* __restrict__ A, const u16* __restrict__ Bt,
                  int m0, int n0, int kt, char* lds, int tid)
{
  char* sA = lds + (kt & 3) * (BM * 64);
  char* sB = lds + 4 * BM * 64 + (kt & 3) * (BN * 64);
  const u16* srcA = A + (size_t)m0 * KD + kt * 32;
#pragma unroll
  for (int i = 0; i < BM / 128; ++i) {
    int ch = i * 512 + tid;
    int r2 = ch >> 3, sub = (ch >> 2) & 1, cp = ch & 3;
    int c = cp ^ (r2 & 3), r = r2 * 2 + sub;
    gload16(srcA + (size_t)r * KD + c * 8, (u16*)(sA + ch * 16));
  }
  const u16* srcB = Bt + (size_t)n0 * KD + kt * 32;
#pragma unroll
  for (int i = 0; i < BN / 128; ++i) {
    int ch = i * 512 + tid;
    int r2 = ch >> 3, sub = (ch >> 2) & 1, cp = ch & 3;
    int c = cp ^ (r2 & 3), r = r2 * 2 + sub;
    gload16(srcB + (size_t)r * KD + c * 8, (u16*)(sB + ch * 16));
  }
}

DEVI int swz_addr(int r, int lhi) {
  return (r >> 1) * 128 + (r & 1) * 64 + ((lhi ^ ((r >> 1) & 3)) << 4);
}

template<int BM, int BN, int WRN, int WCN, int MF, int NF>
DEVI void gemm_ring(const u16* __restrict__ A, const u16* __restrict__ Bt,
                    int m0, int n0, char* lds, f32x4 (&acc)[MF][NF])
{
  constexpr int NTk = KD / 32;              // 64 K-steps
  constexpr int LPB = (BM + BN) / 128;      // gloads per thread per K-step
  const int tid = threadIdx.x, lane = tid & 63, wave = tid >> 6;
  const int wrb = (wave / WCN) * (BM / WRN);
  const int wcb = (wave % WCN) * 64;
  const int lhi = lane >> 4, llo = lane & 15;

  stage32<BM, BN>(A, Bt, m0, n0, 0, lds, tid);
  stage32<BM, BN>(A, Bt, m0, n0, 1, lds, tid);
  stage32<BM, BN>(A, Bt, m0, n0, 2, lds, tid);
  if constexpr (LPB == 4) WAITVM(8); else WAITVM(6);
  __builtin_amdgcn_s_barrier();
  __builtin_amdgcn_sched_barrier(0);

  for (int kt = 0; kt < NTk; ++kt) {
    if (kt + 3 < NTk) stage32<BM, BN>(A, Bt, m0, n0, kt + 3, lds, tid);
    char* sA = lds + (kt & 3) * (BM * 64);
    char* sB = lds + 4 * BM * 64 + (kt & 3) * (BN * 64);
    __builtin_amdgcn_s_setprio(1);
    bf16x8 bfr[NF];
#pragma unroll
    for (int ni = 0; ni < NF; ++ni)
      bfr[ni] = *(const bf16x8*)(sB + swz_addr(wcb + ni * 16 + llo, lhi));
#pragma unroll
    for (int mi = 0; mi < MF; ++mi) {
      bf16x8 af = *(const bf16x8*)(sA + swz_addr(wrb + mi * 16 + llo, lhi));
#pragma unroll
      for (int ni = 0; ni < NF; ++ni)
        acc[mi][ni] = mfma16(af, bfr[ni], acc[mi][ni]);
    }
    __builtin_amdgcn_s_setprio(0);
    if (kt < NTk - 3)       { if constexpr (LPB == 4) WAITVM(8); else WAITVM(6); }
    else if (kt == NTk - 3) { if constexpr (LPB == 4) WAITVM(4); else WAITVM(3); }
    else                    WAITVM(0);
    __builtin_amdgcn_s_barrier();
    __builtin_amdgcn_sched_barrier(0);
  }
}

// ---------------------------------------------------------------------------
// Projections: 256x256 tile, 8 waves (2M x 4N). z=0 Q, z=1 K -> (b,h,s,dk);
// z=2 V -> (b,h,dv,s) (transposed, via LDS-bounce); z=3 gate -> silu.
// All epilogues bounce through LDS for coalesced 16B stores.
// ---------------------------------------------------------------------------
__global__ __launch_bounds__(512, 2) void proj_kernel(
    const u16* __restrict__ xb, const u16* __restrict__ wtBase,
    const float* __restrict__ bq, const float* __restrict__ bk,
    const float* __restrict__ bv, const float* __restrict__ bg,
    u16* __restrict__ qb, u16* __restrict__ kb,
    u16* __restrict__ vtb, u16* __restrict__ gb)
{
  __shared__ __align__(16) char smem[131072];
  const int z = blockIdx.z;
  const u16* Bt = wtBase + (size_t)z * (size_t)KD * HID;
  f32x4 acc[8][4];
  const f32x4 zero = {0.f, 0.f, 0.f, 0.f};
#pragma unroll
  for (int mi = 0; mi < 8; ++mi)
#pragma unroll
    for (int ni = 0; ni < 4; ++ni) acc[mi][ni] = zero;

  const int m0 = blockIdx.x * 256, n0 = blockIdx.y * 256;
  gemm_ring<256, 256, 2, 4, 8, 4>(xb, Bt, m0, n0, smem, acc);

  const int tid = threadIdx.x, lane = tid & 63, wave = tid >> 6;
  const int wr = wave >> 2, wc = wave & 3;
  const int lhi = lane >> 4, llo = lane & 15;
  const float* bias = (z == 0) ? bq : (z == 1) ? bk : (z == 2) ? bv : bg;
  u16* Lb = (u16*)smem;   // 256x256 u16, phys col = c ^ ((row&7)<<3)

  if (z == 2) {
    // transpose in LDS: Lb[n_local][s_local]
#pragma unroll
    for (int mi = 0; mi < 8; ++mi) {
#pragma unroll
      for (int ni = 0; ni < 4; ++ni) {
        int nl = wc * 64 + ni * 16 + llo;
        float bsn = bias[n0 + nl];
#pragma unroll
        for (int r = 0; r < 4; ++r) {
          int sl = wr * 128 + mi * 16 + lhi * 4 + r;
          Lb[nl * 256 + (sl ^ ((nl & 7) << 3))] = f2bf(acc[mi][ni][r] + bsn);
        }
      }
    }
    __syncthreads();
    const int b = m0 >> 11, sbase = m0 & (SS - 1), h0 = n0 >> 7;
#pragma unroll
    for (int jj = 0; jj < 16; ++jj) {
      int id = jj * 512 + tid;
      int nl = id >> 5, c8 = id & 31;
      uint4 v = *(const uint4*)&Lb[nl * 256 + ((c8 * 8) ^ ((nl & 7) << 3))];
      int h = h0 + (nl >> 7), j = nl & 127;
      *(uint4*)(vtb + ((size_t)((b * NH + h) * DV + j)) * SS + sbase + c8 * 8) = v;
    }
  } else {
#pragma unroll
    for (int mi = 0; mi < 8; ++mi) {
#pragma unroll
      for (int ni = 0; ni < 4; ++ni) {
        int colL = wc * 64 + ni * 16 + llo;
        float bsn = bias[n0 + colL];
#pragma unroll
        for (int r = 0; r < 4; ++r) {
          int rowL = wr * 128 + mi * 16 + lhi * 4 + r;
          float c = acc[mi][ni][r] + bsn;
          if (z == 3) c = c / (1.0f + expf(-c));
          Lb[rowL * 256 + (colL ^ ((rowL & 7) << 3))] = f2bf(c);
        }
      }
    }
    __syncthreads();
#pragma unroll
    for (int jj = 0; jj < 16; ++jj) {
      int id = jj * 512 + tid;
      int rr = id >> 5, c8 = id & 31;
      uint4 v = *(const uint4*)&Lb[rr * 256 + ((c8 * 8) ^ ((rr & 7) << 3))];
      int m = m0 + rr, b = m >> 11, s = m & (SS - 1);
      int n = n0 + c8 * 8;
      if (z == 3) {
        *(uint4*)(gb + (size_t)m * HID + n) = v;
      } else {
        int h = n >> 7, j2 = n & 127;
        u16* dst = (z == 0) ? qb : kb;
        *(uint4*)(dst + ((size_t)((b * NH + h) * SS + s)) * DK + j2) = v;
      }
    }
  }
}

// ---------------------------------------------------------------------------
// Retention: per (b,h, 128-row q tile). Stream 64-row K/V tiles with decay
// mask gamma^(n-m) = gamma^n * gamma^-m. 2-phase double-buffered K/V staging.
// Outputs fp32 ret (b,h,s,dv) + atomic per-(b,h) sum/sumsq for GroupNorm.
// ---------------------------------------------------------------------------
__global__ __launch_bounds__(256) void retention_kernel(
    const u16* __restrict__ qb, const u16* __restrict__ kb,
    const u16* __restrict__ vtb, const float* __restrict__ gamma,
    float* __restrict__ ret, float* __restrict__ stats)
{
  // LDS: sK dbuf 2x16KB @0, sV dbuf 2x16KB @32768, sP 4x4KB @65536 = 80KB
  __shared__ __align__(16) char smemR[81920];
  __shared__ float red[8];

  const int bh = blockIdx.y;
  const int n0 = blockIdx.x * 128;
  const int h = bh & (NH - 1);
  const float lg2 = log2f(gamma[h]);

  const int tid = threadIdx.x, lane = tid & 63, wave = tid >> 6;
  const int lhi = lane >> 4, llo = lane & 15;
  const int qrow = n0 + wave * 32;

  // Q fragments in registers (reused across all m tiles)
  const u16* qbase = qb + ((size_t)bh * SS + qrow) * DK;
  bf16x8 aq[2][4];
#pragma unroll
  for (int mi = 0; mi < 2; ++mi)
#pragma unroll
    for (int ks = 0; ks < 4; ++ks)
      aq[mi][ks] = *(const bf16x8*)(qbase + (size_t)(mi * 16 + llo) * DK + ks * 32 + lhi * 8);

  float rdec[2][4];
#pragma unroll
  for (int mi = 0; mi < 2; ++mi)
#pragma unroll
    for (int r = 0; r < 4; ++r)
      rdec[mi][r] = exp2f(lg2 * (float)(qrow + mi * 16 + lhi * 4 + r));

  const f32x4 zero = {0.f, 0.f, 0.f, 0.f};
  f32x4 oacc[2][8];
#pragma unroll
  for (int mi = 0; mi < 2; ++mi)
#pragma unroll
    for (int nj = 0; nj < 8; ++nj) oacc[mi][nj] = zero;

  const u16* kbase = kb + (size_t)bh * SS * DK;
  const u16* vbase = vtb + (size_t)bh * DV * SS;
  const int mtiles = n0 / 64 + 2;

  auto stageKV = [&](int mbase, u16* sk, u16* sv) {
#pragma unroll
    for (int i = 0; i < 4; ++i) {   // K: 64x128, 256B rows, swz (row&15)<<4
      int c = i * 256 + tid;
      int row = c >> 4, scol = c & 15, dcol = scol ^ (row & 15);
      gload16(kbase + (size_t)(mbase + row) * DK + dcol * 8, sk + c * 8);
    }
#pragma unroll
    for (int i = 0; i < 4; ++i) {   // Vt: 128x64, 128B rows, swz (row&7)<<4
      int c = i * 256 + tid;
      int row = c >> 3, scol = c & 7, dcol = scol ^ (row & 7);
      gload16(vbase + (size_t)row * SS + mbase + dcol * 8, sv + c * 8);
    }
  };

  stageKV(0, (u16*)smemR, (u16*)(smemR + 32768));
  asm volatile("s_waitcnt vmcnt(0)" ::: "memory");
  __syncthreads();

  for (int mt = 0; mt < mtiles; ++mt) {
    const int m0 = mt * 64;
    char* cK = smemR + (mt & 1) * 16384;
    char* cV = smemR + 32768 + (mt & 1) * 16384;
    if (mt + 1 < mtiles)
      stageKV(m0 + 64, (u16*)(smemR + ((mt + 1) & 1) * 16384),
              (u16*)(smemR + 32768 + ((mt + 1) & 1) * 16384));

    // QK^T
    f32x4 sacc[2][4];
#pragma unroll
    for (int mi = 0; mi < 2; ++mi)
#pragma unroll
      for (int ni = 0; ni < 4; ++ni) sacc[mi][ni] = zero;
    __builtin_amdgcn_s_setprio(1);
#pragma unroll
    for (int ks = 0; ks < 4; ++ks) {
      const int kbyte = ks * 64 + lhi * 16;
      bf16x8 bk_[4];
#pragma unroll
      for (int ni = 0; ni < 4; ++ni) {
        int row = ni * 16 + llo;
        bk_[ni] = *(const bf16x8*)(cK + row * 256 + (kbyte ^ ((row & 15) << 4)));
      }
#pragma unroll
      for (int mi = 0; mi < 2; ++mi)
#pragma unroll
        for (int ni = 0; ni < 4; ++ni)
          sacc[mi][ni] = mfma16(aq[mi][ks], bk_[ni], sacc[mi][ni]);
    }
    __builtin_amdgcn_s_setprio(0);

    // decay + causal mask + bf16 P into per-wave LDS
    float cfac[4];
#pragma unroll
    for (int ni = 0; ni < 4; ++ni)
      cfac[ni] = exp2f(-lg2 * (float)(m0 + ni * 16 + llo));
    const bool masked = (m0 + 63 > qrow);
    char* myP = smemR + 65536 + wave * 4096;
#pragma unroll
    for (int mi = 0; mi < 2; ++mi) {
#pragma unroll
      for (int ni = 0; ni < 4; ++ni) {
#pragma unroll
        for (int r = 0; r < 4; ++r) {
          int prow = mi * 16 + lhi * 4 + r;
          int pcol = ni * 16 + llo;
          float w = rdec[mi][r] * cfac[ni];
          if (masked && (qrow + prow < m0 + pcol)) w = 0.0f;
          float p = sacc[mi][ni][r] * w;
          *(u16*)(myP + prow * 128 + ((pcol * 2) ^ ((prow & 7) << 4))) = f2bf(p);
        }
      }
    }

    // PV (same-wave LDS write->read; compiler inserts lgkmcnt)
    __builtin_amdgcn_s_setprio(1);
#pragma unroll
    for (int ks2 = 0; ks2 < 2; ++ks2) {
      const int kbyte = ks2 * 64 + lhi * 16;
      bf16x8 pa[2];
#pragma unroll
      for (int mi = 0; mi < 2; ++mi) {
        int row = mi * 16 + llo;
        pa[mi] = *(const bf16x8*)(myP + row * 128 + (kbyte ^ ((row & 7) << 4)));
      }
#pragma unroll
      for (int nj = 0; nj < 8; ++nj) {
        int row = nj * 16 + llo;
        bf16x8 vb = *(const bf16x8*)(cV + row * 128 + (kbyte ^ ((row & 7) << 4)));
#pragma unroll
        for (int mi = 0; mi < 2; ++mi)
          oacc[mi][nj] = mfma16(pa[mi], vb, oacc[mi][nj]);
      }
    }
    __builtin_amdgcn_s_setprio(0);
    asm volatile("s_waitcnt vmcnt(0)" ::: "memory");
    __syncthreads();
  }

  // write ret + local stats
  float lsum = 0.f, lsq = 0.f;
  float* rbase = ret + ((size_t)bh * SS + qrow) * DV;
#pragma unroll
  for (int mi = 0; mi < 2; ++mi) {
#pragma unroll
    for (int nj = 0; nj < 8; ++nj) {
      int prow0 = mi * 16 + lhi * 4;
      int j = nj * 16 + llo;
#pragma unroll
      for (int r = 0; r < 4; ++r) {
        float v = oacc[mi][nj][r];
        rbase[(size_t)(prow0 + r) * DV + j] = v;
        lsum += v; lsq += v * v;
      }
    }
  }
#pragma unroll
  for (int off = 32; off > 0; off >>= 1) {
    lsum += __shfl_down(lsum, off, 64);
    lsq  += __shfl_down(lsq,  off, 64);
  }
  if (lane == 0) { red[wave * 2] = lsum; red[wave * 2 + 1] = lsq; }
  __syncthreads();
  if (tid == 0) {
    float s = red[0] + red[2] + red[4] + red[6];
    float q = red[1] + red[3] + red[5] + red[7];
    atomicAdd(&stats[bh * 2], s);
    atomicAdd(&stats[bh * 2 + 1], q);
  }
}

// ---------------------------------------------------------------------------
// GroupNorm (per b,head over s,dv) * gate -> A2 bf16 (b,s,hid)
// ---------------------------------------------------------------------------
__global__ __launch_bounds__(256) void normgate_kernel(
    const float* __restrict__ ret, const u16* __restrict__ gb,
    const float* __restrict__ stats, const float* __restrict__ gn_w,
    const float* __restrict__ gn_b, u16* __restrict__ a2)
{
  const int idx4 = (blockIdx.x * 256 + threadIdx.x) * 4;
  const int bh = idx4 >> 18;              // / (S*DV)
  const int rem = idx4 & (SS * DV - 1);
  const int s = rem >> 7;
  const int dv = rem & (DV - 1);
  const float inv = 1.0f / (float)(SS * DV);
  float mean = stats[bh * 2] * inv;
  float var = stats[bh * 2 + 1] * inv - mean * mean;
  float rstd = rsqrtf(var + 1e-5f);
  const int b = bh >> 4, h = bh & (NH - 1);
  const int hd = h * DV + dv;
  float4 rv = *(const float4*)(ret + idx4);
  float4 w4 = *(const float4*)(gn_w + hd);
  float4 b4 = *(const float4*)(gn_b + hd);
  size_t gidx = ((size_t)(b * SS + s)) * HID + hd;
  ushort4 g4 = *(const ushort4*)(gb + gidx);
  ushort4 o;
  o.x = f2bf(bf2f(g4.x) * ((rv.x - mean) * rstd * w4.x + b4.x));
  o.y = f2bf(bf2f(g4.y) * ((rv.y - mean) * rstd * w4.y + b4.y));
  o.z = f2bf(bf2f(g4.z) * ((rv.z - mean) * rstd * w4.z + b4.z));
  o.w = f2bf(bf2f(g4.w) * ((rv.w - mean) * rstd * w4.w + b4.w));
  *(ushort4*)(a2 + gidx) = o;
}

// ---------------------------------------------------------------------------
// Final GEMM: out = A2 @ wo + bo, fp32 out. 256x128 tile -> grid 16x16 =
// 256 blocks (1/CU). 8 waves (4M x 2N). Single-pass fp32 bounce epilogue.
// ---------------------------------------------------------------------------
__global__ __launch_bounds__(512, 2) void final_kernel(
    const u16* __restrict__ a2, const u16* __restrict__ woT,
    const float* __restrict__ bo, float* __restrict__ out)
{
  __shared__ __align__(16) char smem[131072];   // ring uses 96KB; bounce 128KB
  f32x4 acc[4][4];
  const f32x4 zero = {0.f, 0.f, 0.f, 0.f};
#pragma unroll
  for (int mi = 0; mi < 4; ++mi)
#pragma unroll
    for (int ni = 0; ni < 4; ++ni) acc[mi][ni] = zero;

  const int m0 = blockIdx.x * 256, n0 = blockIdx.y * 128;
  gemm_ring<256, 128, 4, 2, 4, 4>(a2, woT, m0, n0, smem, acc);

  const int tid = threadIdx.x, lane = tid & 63, wave = tid >> 6;
  const int wr = wave >> 1, wc = wave & 1;
  const int lhi = lane >> 4, llo = lane & 15;
  float* Lf = (float*)smem;   // 256 x 128 fp32, phys col = c ^ ((row&7)<<2)

#pragma unroll
  for (int mi = 0; mi < 4; ++mi) {
#pragma unroll
    for (int ni = 0; ni < 4; ++ni) {
      int colL = wc * 64 + ni * 16 + llo;
      float bn = bo[n0 + colL];
#pragma unroll
      for (int r = 0; r < 4; ++r) {
        int rowL = wr * 64 + mi * 16 + lhi * 4 + r;
        Lf[rowL * 128 + (colL ^ ((rowL & 7) << 2))] = acc[mi][ni][r] + bn;
      }
    }
  }
  __syncthreads();
#pragma unroll
  for (int jj = 0; jj < 16; ++jj) {
    int id = jj * 512 + tid;
    int row = id >> 5, c4 = id & 31;
    int col = c4 * 4;
    float4 v = *(const float4*)&Lf[row * 128 + (col ^ ((row & 7) << 2))];
    *(float4*)(out + (size_t)(m0 + row) * HID + n0 + col) = v;
  }
}

// ---------------------------------------------------------------------------
extern "C" void kernel_launch(void* const* d_in, const int* in_sizes, int n_in,
                              void* d_out, int out_size, void* d_ws, size_t ws_size,
                              hipStream_t stream) {
  const float* x    = (const float*)d_in[0];
  const float* wq   = (const float*)d_in[1];
  const float* bq   = (const float*)d_in[2];
  const float* wk   = (const float*)d_in[3];
  const float* bk   = (const float*)d_in[4];
  const float* wv   = (const float*)d_in[5];
  const float* bv   = (const float*)d_in[6];
  const float* wg   = (const float*)d_in[7];
  const float* bg   = (const float*)d_in[8];
  const float* wo   = (const float*)d_in[9];
  const float* bo   = (const float*)d_in[10];
  const float* gn_w = (const float*)d_in[11];
  const float* gn_b = (const float*)d_in[12];
  const float* gam  = (const float*)d_in[13];

  char* ws = (char*)d_ws;
  // layout (bytes):
  u16* wT    = (u16*)(ws);                  // 5 * 8,388,608   = 41,943,040
  u16* qb    = (u16*)(ws + 41943040);       // 16,777,216
  u16* kbuf  = (u16*)(ws + 58720256);       // 16,777,216
  u16* vtb   = (u16*)(ws + 75497472);       // 16,777,216
  u16* gb    = (u16*)(ws + 92274688);       // 16,777,216
  float* ret = (float*)(ws + 109051904);    // 33,554,432
  float* st  = (float*)(ws + 142606336);    // 256
  u16* a2    = qb;                          // reuse (qb dead after retention)
  u16* xb    = (u16*)ret;                   // reuse (xb dead before retention writes ret)

  hipMemsetAsync(st, 0, 256, stream);
  castx_kernel<<<4096, 256, 0, stream>>>(x, xb);
  wtrans_kernel<<<dim3(64, 64, 5), dim3(32, 8), 0, stream>>>(wq, wk, wv, wg, wo, wT);
  proj_kernel<<<dim3(16, 8, 4), 512, 0, stream>>>(xb, wT, bq, bk, bv, bg, qb, kbuf, vtb, gb);
  retention_kernel<<<dim3(16, 32), 256, 0, stream>>>(qb, kbuf, vtb, gam, ret, st);
  normgate_kernel<<<16384, 256, 0, stream>>>(ret, gb, st, gn_w, gn_b, a2);
  final_kernel<<<dim3(16, 16), 512, 0, stream>>>(a2, wT + (size_t)4 * KD * HID, bo, (float*)d_out);
}